// Round 6
// baseline (161.133 us; speedup 1.0000x reference)
//
#include <hip/hip_runtime.h>
#include <math.h>

#define S_LEN 2048
#define DHEAD 128
#define NHEAD 16
#define QBLK  128                      // per block-phase: 4 waves x 32 q-rows
#define KVBLK 64
#define NW    4
#define ATT_SCALE 0.08838834764831845f // 1/sqrt(128)
#define LOG2E 1.4426950408889634f
#define SHIFT2 11.5f                   // fixed softmax shift in log2 units

// LDS pitches (bf16 elements); bank-checked for the access patterns below.
#define KP 136
#define VP 72
#define PP 72

typedef __attribute__((ext_vector_type(4))) float f32x4;
typedef __attribute__((ext_vector_type(8))) short s16x8;
typedef __attribute__((ext_vector_type(4))) short s16x4;

__device__ __forceinline__ unsigned f2bfu(float f) {
  union { float ff; unsigned u; } x; x.ff = f;
  return (x.u + 0x7fffu + ((x.u >> 16) & 1u)) >> 16;   // RNE f32->bf16
}
__device__ __forceinline__ short f2bf(float f) { return (short)f2bfu(f); }
__device__ __forceinline__ int pack2(float lo, float hi) {
  return (int)(f2bfu(lo) | (f2bfu(hi) << 16));
}

// kv-slot permutation pi(j) = 4*(j&15) + (j>>4), applied identically to P (A-op)
// and V^T (B-op) k-indices -> cancels inside the MFMA dot product. Purpose:
// a lane's 4 softmax outputs (nt=0..3, same l16) become LDS-contiguous -> b64 write.

__global__ __launch_bounds__(256, 2)   // 256 VGPR budget/wave; 2 blocks/CU (LDS 54.3KB)
void alibi_attn_fwd(const float* __restrict__ Qg, const float* __restrict__ Kg,
                    const float* __restrict__ Vg, float* __restrict__ Og)
{
  __shared__ __align__(16) short kt[KVBLK * KP];      // K tile [kv][d]
  __shared__ __align__(16) short vt[DHEAD * VP];      // V^T tile [d][pi(kv)]
  __shared__ __align__(16) short pl[NW * 2][16 * PP]; // P per (wave,M-tile) [row][pi(kv)]

  const int tid  = threadIdx.x;
  const int lane = tid & 63;
  const int w    = tid >> 6;      // wave 0..3 (owns 32 q-rows per phase)
  const int l16  = lane & 15;
  const int lg   = lane >> 4;     // 0..3

  // n = pr*64 + bh: XCD = n&7 = bh&7 (head-local L2). Each block runs q-tile
  // pair {15-pr, pr}: uniform 34 kv-tiles of work for every block.
  const int n    = blockIdx.x;
  const int bh   = n & 63;
  const int pr   = n >> 6;        // 0..7
  const int head = bh & (NHEAD - 1);

  const size_t base = (size_t)bh * S_LEN * DHEAD;
  const float* Q = Qg + base;
  const float* K = Kg + base;
  const float* V = Vg + base;
  float*       O = Og + base;

  const float slope2 = exp2f(-0.5f * (float)(head + 1)) * LOG2E;
  float cn[4];
  #pragma unroll
  for (int nt = 0; nt < 4; ++nt) cn[nt] = (float)(nt * 16) * slope2 - SHIFT2;

  s16x8 ones;
  #pragma unroll
  for (int jj = 0; jj < 8; ++jj) ones[jj] = (short)0x3f80;  // bf16 1.0

  const f32x4 zero4 = {0.f, 0.f, 0.f, 0.f};

  // ---- staging maps (256 threads) ----
  // K: row kr (0..63), d = kd0..kd0+31 (8 f32x4 loads, 4 b128 LDS writes)
  const int kr  = tid >> 2;
  const int kd0 = 32 * (tid & 3);
  // V: rows rowA=32*vsel+vl and rowB=rowA+16 (pi-adjacent), d = vd0..vd0+15
  const int vl   = tid & 15;
  const int vsel = (tid >> 4) & 1;
  const int vd0  = 16 * (tid >> 5);
  const int rowA = 32 * vsel + vl;
  const int rowB = rowA + 16;
  const int vslot = 4 * vl + 2 * vsel;   // pi(rowA); pi(rowB) = vslot+1

  f32x4 ka[8], va[4], vb[4];   // T14 prefetch registers (live across compute)

#define LOAD_TILE(KV0) do {                                           \
    const float* kp_ = K + (size_t)((KV0) + kr) * DHEAD + kd0;        \
    ka[0] = *(const f32x4*)(kp_);      ka[1] = *(const f32x4*)(kp_ + 4);  \
    ka[2] = *(const f32x4*)(kp_ + 8);  ka[3] = *(const f32x4*)(kp_ + 12); \
    ka[4] = *(const f32x4*)(kp_ + 16); ka[5] = *(const f32x4*)(kp_ + 20); \
    ka[6] = *(const f32x4*)(kp_ + 24); ka[7] = *(const f32x4*)(kp_ + 28); \
    const float* va_ = V + (size_t)((KV0) + rowA) * DHEAD + vd0;      \
    const float* vb_ = V + (size_t)((KV0) + rowB) * DHEAD + vd0;      \
    va[0] = *(const f32x4*)(va_);      va[1] = *(const f32x4*)(va_ + 4);  \
    va[2] = *(const f32x4*)(va_ + 8);  va[3] = *(const f32x4*)(va_ + 12); \
    vb[0] = *(const f32x4*)(vb_);      vb[1] = *(const f32x4*)(vb_ + 4);  \
    vb[2] = *(const f32x4*)(vb_ + 8);  vb[3] = *(const f32x4*)(vb_ + 12); \
  } while (0)

  LOAD_TILE(0);   // prefetch first tile of phase 0
  bool first = true;

  for (int ph = 0; ph < 2; ++ph) {
    const int qt = ph ? pr : (15 - pr);
    const int qb = qt * QBLK;
    const int ntiles = 2 * (qt + 1);

    // ---- Q A-fragments, pre-scaled by ATT_SCALE*log2e ----
    s16x8 qf[2][4];
    #pragma unroll
    for (int m = 0; m < 2; ++m) {
      const float* qp = Q + (size_t)(qb + 32*w + 16*m + l16) * DHEAD + 8*lg;
      #pragma unroll
      for (int c = 0; c < 4; ++c) {
        f32x4 a = *(const f32x4*)(qp + 32*c);
        f32x4 b = *(const f32x4*)(qp + 32*c + 4);
        const float sc = ATT_SCALE * LOG2E;
        s16x8 f;
        f[0]=f2bf(a[0]*sc); f[1]=f2bf(a[1]*sc); f[2]=f2bf(a[2]*sc); f[3]=f2bf(a[3]*sc);
        f[4]=f2bf(b[0]*sc); f[5]=f2bf(b[1]*sc); f[6]=f2bf(b[2]*sc); f[7]=f2bf(b[3]*sc);
        qf[m][c] = f;
      }
    }

    f32x4 oacc[2][8];
    f32x4 lacc[2];
    #pragma unroll
    for (int m = 0; m < 2; ++m) {
      #pragma unroll
      for (int dt = 0; dt < 8; ++dt) oacc[m][dt] = zero4;
      lacc[m] = zero4;
    }

    for (int tt = 0; tt < ntiles; ++tt) {
      const int kv0 = tt * KVBLK;

      if (!first) __syncthreads();   // waves done reading previous LDS tile
      first = false;

      // ---- stage K tile (4 b128 writes) ----
      #pragma unroll
      for (int h = 0; h < 4; ++h) {
        s16x8 f;
        f[0]=f2bf(ka[2*h][0]);   f[1]=f2bf(ka[2*h][1]);
        f[2]=f2bf(ka[2*h][2]);   f[3]=f2bf(ka[2*h][3]);
        f[4]=f2bf(ka[2*h+1][0]); f[5]=f2bf(ka[2*h+1][1]);
        f[6]=f2bf(ka[2*h+1][2]); f[7]=f2bf(ka[2*h+1][3]);
        *(s16x8*)&kt[kr * KP + kd0 + 8*h] = f;
      }
      // ---- stage V^T tile into pi slots (16 b32 writes) ----
      #pragma unroll
      for (int e = 0; e < 16; ++e) {
        *(int*)&vt[(vd0 + e) * VP + vslot] = pack2(va[e >> 2][e & 3], vb[e >> 2][e & 3]);
      }
      __syncthreads();

      // prefetch next tile in the flattened (phase0 ++ phase1) sequence
      const bool last = (ph == 1) && (tt == ntiles - 1);
      if (!last) {
        const int nk = (tt + 1 < ntiles) ? (kv0 + KVBLK) : 0;
        LOAD_TILE(nk);
      }

      if (kv0 <= qb + 32*w + 31) {
        // ---- QK^T: each kf read feeds both M-tiles ----
        f32x4 sacc[2][4];
        #pragma unroll
        for (int nt = 0; nt < 4; ++nt) { sacc[0][nt] = zero4; sacc[1][nt] = zero4; }
        __builtin_amdgcn_s_setprio(1);
        #pragma unroll
        for (int c = 0; c < 4; ++c) {
          #pragma unroll
          for (int nt = 0; nt < 4; ++nt) {
            s16x8 kf = *(const s16x8*)&kt[(nt*16 + l16) * KP + 32*c + 8*lg];
            sacc[0][nt] = __builtin_amdgcn_mfma_f32_16x16x32_bf16(qf[0][c], kf, sacc[0][nt], 0, 0, 0);
            sacc[1][nt] = __builtin_amdgcn_mfma_f32_16x16x32_bf16(qf[1][c], kf, sacc[1][nt], 0, 0, 0);
          }
        }
        __builtin_amdgcn_s_setprio(0);

        // ---- softmax (fixed shift, log2 domain); one b64 P-write per (m,r) ----
        #pragma unroll
        for (int m = 0; m < 2; ++m) {
          #pragma unroll
          for (int r = 0; r < 4; ++r) {
            const int i = qb + 32*w + 16*m + 4*lg + r;
            const float b0 = (float)(kv0 + l16 - i) * slope2;
            s16x4 pv;
            #pragma unroll
            for (int nt = 0; nt < 4; ++nt) {
              const int j = kv0 + nt*16 + l16;
              float p = __builtin_amdgcn_exp2f(sacc[m][nt][r] + (b0 + cn[nt]));
              p = (j > i) ? 0.f : p;
              pv[nt] = f2bf(p);
            }
            *(s16x4*)&pl[2*w + m][(4*lg + r) * PP + 4*l16] = pv;   // pi slots
          }
        }

        // ---- PV in pi space; row-sum via ones-MFMA ----
        __builtin_amdgcn_s_setprio(1);
        #pragma unroll
        for (int c2 = 0; c2 < KVBLK/32; ++c2) {
          s16x8 pa0 = *(const s16x8*)&pl[2*w    ][l16 * PP + c2*32 + 8*lg];
          s16x8 pa1 = *(const s16x8*)&pl[2*w + 1][l16 * PP + c2*32 + 8*lg];
          lacc[0] = __builtin_amdgcn_mfma_f32_16x16x32_bf16(pa0, ones, lacc[0], 0, 0, 0);
          lacc[1] = __builtin_amdgcn_mfma_f32_16x16x32_bf16(pa1, ones, lacc[1], 0, 0, 0);
          #pragma unroll
          for (int dt = 0; dt < 8; ++dt) {
            s16x8 bv = *(const s16x8*)&vt[(dt*16 + l16) * VP + c2*32 + 8*lg];
            oacc[0][dt] = __builtin_amdgcn_mfma_f32_16x16x32_bf16(pa0, bv, oacc[0][dt], 0, 0, 0);
            oacc[1][dt] = __builtin_amdgcn_mfma_f32_16x16x32_bf16(pa1, bv, oacc[1][dt], 0, 0, 0);
          }
        }
        __builtin_amdgcn_s_setprio(0);
      }
    }

    // ---- epilogue for this phase ----
    #pragma unroll
    for (int m = 0; m < 2; ++m) {
      #pragma unroll
      for (int r = 0; r < 4; ++r) {
        const float inv = 1.0f / lacc[m][r];
        float* op = O + (size_t)(qb + 32*w + 16*m + 4*lg + r) * DHEAD + l16;
        #pragma unroll
        for (int dt = 0; dt < 8; ++dt) op[dt * 16] = oacc[m][dt][r] * inv;
      }
    }
  }
}

extern "C" void kernel_launch(void* const* d_in, const int* in_sizes, int n_in,
                              void* d_out, int out_size, void* d_ws, size_t ws_size,
                              hipStream_t stream) {
  (void)in_sizes; (void)n_in; (void)out_size; (void)d_ws; (void)ws_size;
  const float* q = (const float*)d_in[0];
  const float* k = (const float*)d_in[1];
  const float* v = (const float*)d_in[2];
  float* o = (float*)d_out;
  dim3 grid(512);    // 64 heads x 8 uniform q-tile pairs; 2 blocks/CU
  dim3 block(256);
  alibi_attn_fwd<<<grid, block, 0, stream>>>(q, k, v, o);
}